// Round 4
// baseline (124.183 us; speedup 1.0000x reference)
//
#include <hip/hip_runtime.h>
#include <hip/hip_bf16.h>

#define D 128
#define MARGIN 0.5f
#define NSPLIT 16      // j-splits; block j-window = 8192/16 = 512 cols
#define JSPAN 512      // n / NSPLIT (n = 8192 fixed by harness)

typedef __attribute__((ext_vector_type(8))) short bf16x8;
typedef __attribute__((ext_vector_type(4))) float f32x4;

// ---------------- prep: bf16 convert + sq + out init ----------------
__global__ void prep_kernel(const float* __restrict__ x,
                            float* __restrict__ sq,
                            __hip_bfloat16* __restrict__ xb,
                            float* __restrict__ out, int n) {
    int tid = threadIdx.x;
    int row = blockIdx.x * 4 + (tid >> 6);
    int lane = tid & 63;
    const float2* xr = (const float2*)(x + (size_t)row * D);
    float2 v = xr[lane];
    __hip_bfloat162 b2;
    b2.x = __float2bfloat16(v.x);
    b2.y = __float2bfloat16(v.y);
    ((__hip_bfloat162*)(xb + (size_t)row * D))[lane] = b2;
    float s = v.x * v.x + v.y * v.y;
    #pragma unroll
    for (int o = 32; o > 0; o >>= 1) s += __shfl_xor(s, o, 64);
    if (lane == 0) sq[row] = s;
    if (blockIdx.x == 0 && tid == 0) *out = 0.0f;
}

// ---------------- gram: barrier-free L2-direct (R8 ablation) ----------------
// R5-R7 lesson: gram was insensitive to LDS-traffic halving AND counted-vmcnt
// restructure, but sensitive to occupancy -> stall/sync-dominated, not
// pipe-bound. This version DELETES the sync structure: xb (2MB) fits every
// XCD's 4MB L2, so B-fragments are gathered directly from global (each
// 4-lane quad group covers one 64B line exactly; the block's 4 waves read
// the identical j-window -> L1 cross-wave reuse). No LDS ring, no
// global_load_lds, no per-phase barriers, no vmcnt waits. One __syncthreads
// total (sqs/tgs stage). End atomics replaced by plain per-(row,jsplit)
// partial stores (pap/pan slabs), reduced in final_kernel -- removes the
// 262K device-atomic tail convoy.
// Per iter (32 j-cols): 8 global b128 gathers + 16 MFMA (4 indep acc
// chains) + ~100 VALU epilogue. Floors: MFMA 8.3us, VALU 5.3us, L2 <8us,
// all overlappable via 16 free-running waves/CU.
__launch_bounds__(256, 4)
__global__ void gram_kernel(const __hip_bfloat16* __restrict__ xb,
                            const float* __restrict__ sq,
                            const int* __restrict__ tgt,
                            float* __restrict__ pap,
                            float* __restrict__ pan, int n) {
    __shared__ float sqs[JSPAN];
    __shared__ int   tgs[JSPAN];

    const int tid  = threadIdx.x;
    const int wid  = tid >> 6;
    const int lane = tid & 63;
    const int quad = lane >> 4;
    const int l    = lane & 15;
    const int i0   = blockIdx.x * 128;
    const int j0   = blockIdx.y * JSPAN;
    const int rowbase = i0 + wid * 32;

    // stage j-window metadata (coalesced); only barrier in the kernel below
    sqs[tid]       = sq[j0 + tid];
    sqs[tid + 256] = sq[j0 + tid + 256];
    tgs[tid]       = tgt[j0 + tid];
    tgs[tid + 256] = tgt[j0 + tid + 256];

    // A fragments, register-resident: lane holds A[m=l][k=quad*8+r]
    bf16x8 afrag[2][4];
    {
        const __hip_bfloat16* abase = xb + (size_t)(rowbase + l) * D + quad * 8;
        #pragma unroll
        for (int mt = 0; mt < 2; ++mt)
            #pragma unroll
            for (int ks = 0; ks < 4; ++ks)
                afrag[mt][ks] = *(const bf16x8*)(abase + (size_t)mt * 16 * D + ks * 32);
    }

    int li[2][4];
    #pragma unroll
    for (int mt = 0; mt < 2; ++mt)
        #pragma unroll
        for (int reg = 0; reg < 4; ++reg)
            li[mt][reg] = tgt[rowbase + mt * 16 + quad * 4 + reg];

    float lap[8], lan[8];
    #pragma unroll
    for (int k = 0; k < 8; ++k) { lap[k] = -1e30f; lan[k] = 1e30f; }

    __syncthreads();   // sqs/tgs visible

    // B-frag gather: lane (quad,l) reg r needs xb[j = jb+sub*16+l][k = (ks*4+quad)*8 + r]
    // -> 16B chunk at row*(256B) + (ks*4+quad)*16. Quad group spans one 64B line.
    const char* xbb = (const char*)xb + (size_t)j0 * 256;

    for (int it = 0; it < 16; ++it) {      // 32 j-cols per iter
        const int jb = it * 32;
        bf16x8 bfr[2][4];
        #pragma unroll
        for (int sub = 0; sub < 2; ++sub)
            #pragma unroll
            for (int ks = 0; ks < 4; ++ks)
                bfr[sub][ks] = *(const bf16x8*)(
                    xbb + (size_t)(jb + sub * 16 + l) * 256 + (ks * 4 + quad) * 16);

        f32x4 acc[2][2];
        #pragma unroll
        for (int sub = 0; sub < 2; ++sub)
            #pragma unroll
            for (int mt = 0; mt < 2; ++mt)
                acc[sub][mt] = (f32x4){0.f, 0.f, 0.f, 0.f};

        __builtin_amdgcn_s_setprio(1);
        #pragma unroll
        for (int ks = 0; ks < 4; ++ks)
            #pragma unroll
            for (int sub = 0; sub < 2; ++sub)
                #pragma unroll
                for (int mt = 0; mt < 2; ++mt)
                    acc[sub][mt] = __builtin_amdgcn_mfma_f32_16x16x32_bf16(
                        afrag[mt][ks], bfr[sub][ks], acc[sub][mt], 0, 0, 0);
        __builtin_amdgcn_s_setprio(0);

        #pragma unroll
        for (int sub = 0; sub < 2; ++sub) {
            float sjc = sqs[jb + sub * 16 + l];
            int   tjc = tgs[jb + sub * 16 + l];
            #pragma unroll
            for (int mt = 0; mt < 2; ++mt)
                #pragma unroll
                for (int reg = 0; reg < 4; ++reg) {
                    float t0 = fmaf(-2.0f, acc[sub][mt][reg], sjc);
                    bool s0 = (li[mt][reg] == tjc);
                    lap[mt * 4 + reg] = fmaxf(lap[mt * 4 + reg], s0 ? t0 : -1e30f);
                    lan[mt * 4 + reg] = fminf(lan[mt * 4 + reg], s0 ? 1e30f : t0);
                }
        }
    }

    // reduce across 16 column-lanes (xor<16 stays within quad group),
    // then plain partial store (no atomics)
    #pragma unroll
    for (int mt = 0; mt < 2; ++mt)
        #pragma unroll
        for (int reg = 0; reg < 4; ++reg) {
            float p = lap[mt * 4 + reg], q = lan[mt * 4 + reg];
            #pragma unroll
            for (int o = 1; o < 16; o <<= 1) {
                p = fmaxf(p, __shfl_xor(p, o, 64));
                q = fminf(q, __shfl_xor(q, o, 64));
            }
            if (l == mt * 4 + reg) {   // one writer lane per quad
                int gi = rowbase + mt * 16 + quad * 4 + reg;
                float s = sq[gi];
                pap[(size_t)blockIdx.y * n + gi] = fmaxf(s + p, 0.0f);
                pan[(size_t)blockIdx.y * n + gi] = fmaxf(s + q, 0.0f);
            }
        }
}

// ---------------- final: reduce partials, sum relu(ap - an + margin) -----
__global__ void final_kernel(const float* __restrict__ pap,
                             const float* __restrict__ pan,
                             float* __restrict__ out, int n) {
    int i = blockIdx.x * blockDim.x + threadIdx.x;
    float p = pap[i], q = pan[i];
    #pragma unroll
    for (int s = 1; s < NSPLIT; ++s) {
        p = fmaxf(p, pap[(size_t)s * n + i]);
        q = fminf(q, pan[(size_t)s * n + i]);
    }
    float v = fmaxf(p - q + MARGIN, 0.0f);
    #pragma unroll
    for (int o = 32; o > 0; o >>= 1) v += __shfl_xor(v, o, 64);
    __shared__ float ws[4];
    int lane = threadIdx.x & 63, w = threadIdx.x >> 6;
    if (lane == 0) ws[w] = v;
    __syncthreads();
    if (threadIdx.x == 0) atomicAdd(out, ws[0] + ws[1] + ws[2] + ws[3]);
}

extern "C" void kernel_launch(void* const* d_in, const int* in_sizes, int n_in,
                              void* d_out, int out_size, void* d_ws, size_t ws_size,
                              hipStream_t stream) {
    const float* x   = (const float*)d_in[0];
    const int*   tgt = (const int*)d_in[1];
    float* out = (float*)d_out;
    const int n = in_sizes[1];              // 8192

    // ws layout: sq [n*4] | pap [n*NSPLIT*4] | pan [n*NSPLIT*4] | xb [n*D*2]
    float*          sq  = (float*)d_ws;
    float*          pap = (float*)((char*)d_ws + (size_t)n * 4);
    float*          pan = (float*)((char*)d_ws + (size_t)n * 4 + (size_t)n * NSPLIT * 4);
    __hip_bfloat16* xb  = (__hip_bfloat16*)((char*)d_ws + (size_t)n * 4 + (size_t)n * NSPLIT * 8);

    prep_kernel<<<n / 4, 256, 0, stream>>>(x, sq, xb, out, n);
    dim3 grid(n / 128, NSPLIT);
    gram_kernel<<<grid, 256, 0, stream>>>(xb, sq, tgt, pap, pan, n);
    final_kernel<<<n / 256, 256, 0, stream>>>(pap, pan, out, n);
}